// Round 10
// baseline (164.602 us; speedup 1.0000x reference)
//
#include <hip/hip_runtime.h>
#include <hip/hip_bf16.h>
#include <stdint.h>

// Problem: feats[8,1024,32,32]f32, conv_w[256,1024]f32, conv_b[256]f32,
// codebook[16384,256]f32 -> z_q[8,256,32,32]f32 (2097152) + loss scalar.
//
// Round-21 design (attacking the ~116 us OUTSIDE gemm2):
//  - featsT round-trip ELIMINATED: gemm1 stages A directly from feats f32.
//    feats[b][c][s] is s-contiguous = the lanes-along-s direction the
//    A-fragment LDS layout wants: per 4-c group, 4 coalesced 256B scalar
//    loads + cvt + one ds_write_b64. Bit-identical values to the old
//    featsT path (same f2bf).
//  - zb round-trip ELIMINATED: gemm1 computes zsq[i] = sum_e z^2 in f32
//    from its accumulators (16-lane shfl reduce + 1 atomicAdd per row).
//    k_final reads zsq (32 KB) instead of zb (4 MB) + reduce pass.
//  - prep shrinks 2432 -> 384 blocks (cbs8 + W2 + best/zsq/lossw init).
//  - gemm2 unchanged from r20 (46.4 us; i8 MFMA + int fold).

typedef float f32x4 __attribute__((ext_vector_type(4)));
typedef int i32x4 __attribute__((ext_vector_type(4)));
typedef int i32x16 __attribute__((ext_vector_type(16)));
typedef short s16x8 __attribute__((ext_vector_type(8)));

__device__ __forceinline__ void gl2lds16(const void* g, void* l) {
  __builtin_amdgcn_global_load_lds(
      (const __attribute__((address_space(1))) void*)g,
      (__attribute__((address_space(3))) void*)l, 16, 0, 0);
}

__device__ __forceinline__ unsigned short f2bf(float f) {
  unsigned u = __float_as_uint(f);
  u = u + 0x7FFFu + ((u >> 16) & 1u);
  return (unsigned short)(u >> 16);
}

__device__ __forceinline__ ushort4 cvt4(float4 v) {
  ushort4 o;
  o.x = f2bf(v.x); o.y = f2bf(v.y); o.z = f2bf(v.z); o.w = f2bf(v.w);
  return o;
}

// Prep, 384 blocks x 256 thr.
// [0,256):    codebook -> cbs8 (i8, scale 127*16384) in 32x32x32 A-fragment
//             order. Block jt = 64 j. fl = lp*256+t in [0,1024) maps
//             [ks 8][fr 2][lane 64]: lane holds
//             A[j=jt*64+fr*32+(lane&31)][k=ks*32+(lane>>5)*16 ..+16]
//             blocks 0-7 additionally init best = INT_MIN, zsq = 0.
// [256,384):  conv_w -> W2 bf16, 8 elem/thread
__global__ void k_prep(const float* __restrict__ cbk, const float* __restrict__ Wsrc,
                       signed char* __restrict__ cbs8, unsigned short* __restrict__ W2,
                       float* __restrict__ lossw, int* __restrict__ best,
                       float* __restrict__ zsq) {
  int blk = blockIdx.x, t = threadIdx.x;
  if (blk == 0 && t < 2) ((int*)lossw)[t] = 0;
  if (blk < 8) {
    #pragma unroll
    for (int k = 0; k < 4; ++k) {
      best[blk * 1024 + k * 256 + t] = (int)0x80000000;
      zsq[blk * 1024 + k * 256 + t] = 0.0f;
    }
  }
  if (blk < 256) {
    int jt = blk;
    #pragma unroll
    for (int lp = 0; lp < 4; ++lp) {
      int fl = lp * 256 + t;  // [0,1024)
      int ks = fl >> 7, fr = (fl >> 6) & 1, lane = fl & 63;
      int j = jt * 64 + fr * 32 + (lane & 31);
      int k = ks * 32 + (lane >> 5) * 16;
      const float* src = cbk + (size_t)j * 256 + k;
      int w4[4];
      #pragma unroll
      for (int q4 = 0; q4 < 4; ++q4) {
        float4 v = *(const float4*)(src + q4 * 4);
        int b0 = __float2int_rn(v.x * 2080768.0f);  // 127*16384
        int b1 = __float2int_rn(v.y * 2080768.0f);
        int b2 = __float2int_rn(v.z * 2080768.0f);
        int b3 = __float2int_rn(v.w * 2080768.0f);
        w4[q4] = (b0 & 255) | ((b1 & 255) << 8) | ((b2 & 255) << 16) | ((b3 & 255) << 24);
      }
      int4* dst = (int4*)(cbs8 + (size_t)jt * 16384 + (size_t)fl * 16);
      *dst = make_int4(w4[0], w4[1], w4[2], w4[3]);
    }
  } else {
    size_t base = (size_t)(blk - 256) * 2048 + t * 8;
    float4 v0 = *(const float4*)(Wsrc + base);
    float4 v1 = *(const float4*)(Wsrc + base + 4);
    *(ushort4*)(W2 + base) = cvt4(v0);
    *(ushort4*)(W2 + base + 4) = cvt4(v1);
  }
}

// GEMM1: z[i][e] = sum_c feats[i][c]*W[e][c] + b[e] (K=1024) -> z8 [i][256] i8
// (scale 16, for gemm2) + zsq[i] = sum_e z^2 (f32, for the loss).
// A staged DIRECTLY from feats f32: per kt, thread (w,l) handles c-groups
// csub = 4w+16r: 4 coalesced 256B loads (lanes along s) + cvt -> ushort4 ->
// ds_write_b64 at [kp=csub>>3][s=l][halves (csub&4)..+3]. Same fragment
// layout as before (bit-identical to the old featsT path).
// BM=BN=64, BK=128, 4 waves 2x2 (wave 32x32), grid (4,128). LDS 2 x 16 KB.
__global__ __launch_bounds__(256, 2)
void k_gemm1(const float* __restrict__ feats, const unsigned short* __restrict__ Bw,
             const float* __restrict__ bias, signed char* __restrict__ z8,
             float* __restrict__ zsq) {
  __shared__ __align__(16) uint8_t lds[2048 * 16];
  uint8_t* ldsA = lds;
  uint8_t* ldsB = lds + 1024 * 16;
  const int t = threadIdx.x, w = t >> 6, l = t & 63;
  const int wy = w >> 1, wx = w & 1, l15 = l & 15, q = l >> 4;
  const int ib = blockIdx.y * 64, eb = blockIdx.x * 64;
  const int b1024 = (ib >> 10) * 1024, s0 = ib & 1023;
  f32x4 acc[2][2] = {};
  for (int kt = 0; kt < 8; ++kt) {
    int c0 = kt * 128;
    __syncthreads();
    // A: direct from feats (f32 -> bf16), coalesced lanes-along-s
    #pragma unroll
    for (int r = 0; r < 8; ++r) {
      int csub = 4 * w + 16 * r;  // multiple of 4 in [0,124]
      const float* src = feats + (size_t)(b1024 + c0 + csub) * 1024 + s0 + l;
      float4 v;
      v.x = src[0]; v.y = src[1024]; v.z = src[2048]; v.w = src[3072];
      *(ushort4*)(ldsA + ((csub >> 3) * 64 + l) * 16 + (csub & 4) * 2) = cvt4(v);
    }
    // B: W2 bf16 via global_load_lds
    #pragma unroll
    for (int r = 0; r < 4; ++r) {
      int P = t + 256 * r;  // kp = P>>6, e = P&63; layout [kp][e][8]
      gl2lds16(Bw + (size_t)(eb + (P & 63)) * 1024 + c0 + (P >> 6) * 8, ldsB + P * 16);
    }
    __syncthreads();
    #pragma unroll
    for (int s = 0; s < 4; ++s) {
      s16x8 a[2], b[2];
      #pragma unroll
      for (int fr = 0; fr < 2; ++fr)
        a[fr] = *(const s16x8*)(ldsA + ((s * 4 + q) * 64 + wy * 32 + fr * 16 + l15) * 16);
      #pragma unroll
      for (int fc = 0; fc < 2; ++fc)
        b[fc] = *(const s16x8*)(ldsB + ((s * 4 + q) * 64 + wx * 32 + fc * 16 + l15) * 16);
      #pragma unroll
      for (int fr = 0; fr < 2; ++fr)
        #pragma unroll
        for (int fc = 0; fc < 2; ++fc)
          acc[fr][fc] = __builtin_amdgcn_mfma_f32_16x16x32_bf16(a[fr], b[fc], acc[fr][fc], 0, 0, 0);
    }
  }
  // epilogue: z8 store + zsq partials
  float zv[2][2][4];
  #pragma unroll
  for (int fc = 0; fc < 2; ++fc) {
    int e = eb + wx * 32 + fc * 16 + l15;
    float bv = bias[e];
    #pragma unroll
    for (int fr = 0; fr < 2; ++fr)
      #pragma unroll
      for (int r = 0; r < 4; ++r) {
        float zf = acc[fr][fc][r] + bv;
        zv[fc][fr][r] = zf;
        int i = ib + wy * 32 + fr * 16 + q * 4 + r;
        int qv = __float2int_rn(zf * 16.0f);
        qv = qv > 127 ? 127 : (qv < -127 ? -127 : qv);
        z8[(size_t)i * 256 + e] = (signed char)qv;
      }
  }
  #pragma unroll
  for (int fr = 0; fr < 2; ++fr)
    #pragma unroll
    for (int r = 0; r < 4; ++r) {
      float p = zv[0][fr][r] * zv[0][fr][r] + zv[1][fr][r] * zv[1][fr][r];
      p += __shfl_xor(p, 1, 64);
      p += __shfl_xor(p, 2, 64);
      p += __shfl_xor(p, 4, 64);
      p += __shfl_xor(p, 8, 64);
      if (l15 == 0)
        atomicAdd(&zsq[ib + wy * 32 + fr * 16 + q * 4 + r], p);
    }
}

// GEMM2 + argmax in INT8, 32x32x32 j-stream. A = cbs8 (fragment order),
// B = z8 [8192 i][256] staged in LDS (32 KB). 256 thr / 4 waves, i-tile 128.
// Wave tile 64j x 128i: acc[2][4] = 128 AGPR, launch_bounds(256,2), 8 ks
// steps (K=32 each), unroll 2.
// INT fold: p = (acc<<9) + (511 - slot); exact monotone (|acc| < 2^22),
// paired v_max3_i32 = 1.5 VALU/score. Winner decoded once per fc ->
// float bit-encode -> csh/atomicMax unchanged. (r20: 46.4 us)
__global__ __launch_bounds__(256, 2)
void k_gemm2(const signed char* __restrict__ cbs8, const signed char* __restrict__ z8,
             int* __restrict__ best) {
  __shared__ __align__(16) uint8_t ldsB[32768];  // [kseg 16][i 128][16B]
  __shared__ int csh[4][128];
  const int t = threadIdx.x, w = t >> 6, l = t & 63;
  const int l31 = l & 31, h = l >> 5;
  const int ib = blockIdx.y * 128;
  // stage z8 tile: packet P -> i = P&127, kseg = P>>7 (16B per packet)
  #pragma unroll
  for (int r = 0; r < 8; ++r) {
    int P = t + 256 * r;
    gl2lds16(z8 + (size_t)(ib + (P & 127)) * 256 + (P >> 7) * 16, ldsB + P * 16);
  }
  int ibest[4];
  #pragma unroll
  for (int fc = 0; fc < 4; ++fc) ibest[fc] = (int)0x80000000;
  __syncthreads();
  const uint8_t* bbase = ldsB + (h * 128 + l31) * 16;  // + ks*4096 + fc*512
  #pragma unroll 1
  for (int js = 0; js < 2; ++js) {
    const int jtile = blockIdx.x * 8 + js * 4 + w;  // 64-j tile index
    const uint8_t* abase = (const uint8_t*)cbs8 + (size_t)jtile * 16384 + l * 16;
    i32x16 acc[2][4] = {};  // [fr j-half][fc i-quarter]
    #pragma unroll 2
    for (int ks = 0; ks < 8; ++ks) {
      i32x4 a0 = *(const i32x4*)(abase + (ks * 2) * 1024);
      i32x4 a1 = *(const i32x4*)(abase + (ks * 2 + 1) * 1024);
      i32x4 b0 = *(const i32x4*)(bbase + ks * 4096);
      i32x4 b1 = *(const i32x4*)(bbase + ks * 4096 + 512);
      i32x4 b2 = *(const i32x4*)(bbase + ks * 4096 + 1024);
      i32x4 b3 = *(const i32x4*)(bbase + ks * 4096 + 1536);
      acc[0][0] = __builtin_amdgcn_mfma_i32_32x32x32_i8(a0, b0, acc[0][0], 0, 0, 0);
      acc[1][0] = __builtin_amdgcn_mfma_i32_32x32x32_i8(a1, b0, acc[1][0], 0, 0, 0);
      acc[0][1] = __builtin_amdgcn_mfma_i32_32x32x32_i8(a0, b1, acc[0][1], 0, 0, 0);
      acc[1][1] = __builtin_amdgcn_mfma_i32_32x32x32_i8(a1, b1, acc[1][1], 0, 0, 0);
      acc[0][2] = __builtin_amdgcn_mfma_i32_32x32x32_i8(a0, b2, acc[0][2], 0, 0, 0);
      acc[1][2] = __builtin_amdgcn_mfma_i32_32x32x32_i8(a1, b2, acc[1][2], 0, 0, 0);
      acc[0][3] = __builtin_amdgcn_mfma_i32_32x32x32_i8(a0, b3, acc[0][3], 0, 0, 0);
      acc[1][3] = __builtin_amdgcn_mfma_i32_32x32x32_i8(a1, b3, acc[1][3], 0, 0, 0);
    }
    // int fold: slot = js*256 + fr*32 + ((rg&3)+8*(rg>>2)); code = 511-slot
    const int cbase = 511 - js * 256;
    #pragma unroll
    for (int fc = 0; fc < 4; ++fc) {
      int bb = ibest[fc];
      #pragma unroll
      for (int fr = 0; fr < 2; ++fr) {
        const int c1 = cbase - fr * 32;
        #pragma unroll
        for (int rg = 0; rg < 16; rg += 2) {
          int c0 = c1 - ((rg & 3) + 8 * (rg >> 2));  // rg even; rg+1 -> c0-1
          int p0 = (int)(((unsigned)acc[fr][fc][rg] << 9) + (unsigned)c0);
          int p1 = (int)(((unsigned)acc[fr][fc][rg + 1] << 9) + (unsigned)(c0 - 1));
          bb = max(max(p0, p1), bb);  // v_max3_i32
        }
      }
      ibest[fc] = bb;
    }
  }
  // decode winner per fc -> global float encode; reduce over h; atomicMax.
  const float inv = 1.0f / 33292288.0f;  // 1/(16*127*16384)
  const int jbase = blockIdx.x * 512 + w * 64 + 4 * h;
  #pragma unroll
  for (int fc = 0; fc < 4; ++fc) {
    int p = ibest[fc];
    int accw = p >> 9;               // exact (code >= 0)
    int loc = 511 - (p & 511);       // js*256 + fr*32 + joff
    int j = jbase + loc;
    float s = fmaf((float)accw, inv, 3.0f);
    int gb = (int)(((unsigned)__float_as_int(s) << 14) + (unsigned)(16383 - j));
    int bb = max(gb, __shfl_xor(gb, 32, 64));
    if (l < 32) csh[w][fc * 32 + l31] = bb;
  }
  __syncthreads();
  if (t < 128) {
    int m0 = max(max(csh[0][t], csh[1][t]), max(csh[2][t], csh[3][t]));
    atomicMax(&best[ib + t], m0);
  }
}

// Final: decode best -> idx, loss from zsq, LDS-staged coalesced gather.
// 256 blocks x 256 thr; block = (b, s0) covering 32 rows.
// Loss: dist_i = zsq[i] - (best>>14)*2^-20; last block writes the scalar.
// Gather: phase A reads codebook rows as 256B bursts -> tile[32][257];
// phase B writes out[b][e][s0+sl] in 128B contiguous runs (pad 257).
__global__ void k_final(const float* __restrict__ cbk, const float* __restrict__ zsq,
                        const int* __restrict__ best, float* __restrict__ lossw,
                        float* __restrict__ out) {
  __shared__ float tile[32][257];
  __shared__ int lidx[32];
  int blk = blockIdx.x, t = threadIdx.x;
  int b = blk >> 5, s0 = (blk & 31) * 32;
  int gi0 = b * 1024 + s0;
  float d = 0.0f;
  if (t < 32) {
    int bv = best[gi0 + t];
    lidx[t] = 16383 - (bv & 0x3FFF);
    d = zsq[gi0 + t] - (float)(bv >> 14) * (1.0f / 1048576.0f);  // 2*score
  }
  if (t < 64) {
    d += __shfl_down(d, 16, 64);
    d += __shfl_down(d, 8, 64);
    d += __shfl_down(d, 4, 64);
    d += __shfl_down(d, 2, 64);
    d += __shfl_down(d, 1, 64);
  }
  if (t == 0) {
    atomicAdd(lossw, d);
    __threadfence();
    int cnt = atomicAdd((int*)lossw + 1, 1);
    if (cnt == 255) {
      __threadfence();
      float total = atomicAdd(lossw, 0.0f);
      out[2097152] = 1.25f * total * (1.0f / 2097152.0f);
    }
  }
  __syncthreads();  // lidx ready
  int w = t >> 6, l = t & 63;
  #pragma unroll
  for (int rr = 0; rr < 8; ++rr) {
    int r = w * 8 + rr;
    const float* src = cbk + (size_t)lidx[r] * 256;
    #pragma unroll
    for (int k = 0; k < 4; ++k)
      tile[r][l + 64 * k] = src[l + 64 * k];
  }
  __syncthreads();
  int sl = t & 31, eg = t >> 5;  // eg 0..7
  size_t ob = (size_t)b * 262144 + s0 + sl;
  #pragma unroll
  for (int k = 0; k < 32; ++k) {
    int e = eg + 8 * k;
    out[ob + (size_t)e * 1024] = tile[sl][e];
  }
}

extern "C" void kernel_launch(void* const* d_in, const int* in_sizes, int n_in,
                              void* d_out, int out_size, void* d_ws, size_t ws_size,
                              hipStream_t stream) {
  const float* feats  = (const float*)d_in[0];
  const float* conv_w = (const float*)d_in[1];
  const float* conv_b = (const float*)d_in[2];
  const float* cbk    = (const float*)d_in[3];
  float* out = (float*)d_out;
  char* ws = (char*)d_ws;
  // workspace layout (bytes), ~6.9 MB total
  unsigned short* W2    = (unsigned short*)(ws);                   //    524,288
  signed char*    cbs8  = (signed char*)(ws + 524288);             //  4,194,304
  signed char*    z8    = (signed char*)(ws + 4718592);            //  2,097,152
  int*            best  = (int*)(ws + 6815744);                    //     32,768
  float*          zsq   = (float*)(ws + 6848512);                  //     32,768
  float*          lossw = (float*)(ws + 6881280);                  //        256

  k_prep<<<384, 256, 0, stream>>>(cbk, conv_w, cbs8, W2, lossw, best, zsq);
  k_gemm1<<<dim3(4, 128), 256, 0, stream>>>(feats, W2, conv_b, z8, zsq);
  k_gemm2<<<dim3(32, 64), 256, 0, stream>>>(cbs8, z8, best);
  k_final<<<256, 256, 0, stream>>>(cbk, zsq, best, lossw, out);
}